// Round 11
// baseline (925.461 us; speedup 1.0000x reference)
//
#include <hip/hip_runtime.h>
#include <hip/hip_bf16.h>
#include <stdint.h>

#define D 128
#define LAYERS 5
#define BN_EPS 1e-5f

typedef unsigned int uint32;
typedef __bf16 bf16x8 __attribute__((ext_vector_type(8)));
typedef float f32x4 __attribute__((ext_vector_type(4)));
typedef float f32x2 __attribute__((ext_vector_type(2)));
typedef uint32 u32x2 __attribute__((ext_vector_type(2)));
typedef uint32 u32x4 __attribute__((ext_vector_type(4)));

// fp32 -> bf16 bits, round-to-nearest-even
__device__ inline unsigned short f2bf(float f) {
    uint32 u = __float_as_uint(f);
    return (unsigned short)((u + 0x7fffu + ((u >> 16) & 1u)) >> 16);
}
__device__ inline float bflo(uint32 p) { return __uint_as_float(p << 16); }
__device__ inline float bfhi(uint32 p) { return __uint_as_float(p & 0xffff0000u); }
__device__ inline uint32 pack2(float a, float b) {
    return (uint32)f2bf(a) | ((uint32)f2bf(b) << 16);
}

// ---------------- edge_index layout detection ----------------

__global__ void detect_kernel(const int* __restrict__ ei, int* __restrict__ flag) {
    if (threadIdx.x == 0 && blockIdx.x == 0) {
        int allz = 1;
#pragma unroll
        for (int i = 0; i < 16; ++i) allz &= (ei[2 * i + 1] == 0);
        *flag = allz;  // 1 => int64 layout, 0 => int32 layout
    }
}

// ---------------- CSR build (dst -> incoming edges) ----------------

__global__ __launch_bounds__(256) void hist_kernel(const int* __restrict__ ei,
                                                   const int* __restrict__ flag,
                                                   int* __restrict__ deg, int E, int n) {
    int e = blockIdx.x * blockDim.x + threadIdx.x;
    if (e >= E) return;
    int is64 = *flag;
    int d = is64 ? ei[2 * ((size_t)E + e)] : ei[E + e];
    if ((unsigned)d < (unsigned)n) atomicAdd(&deg[d], 1);
}

__global__ __launch_bounds__(1024) void scan_kernel(const int* __restrict__ deg,
                                                    int* __restrict__ off, int n) {
    __shared__ int tsum[1024];
    int t = threadIdx.x;
    int CH = (n + 1023) >> 10;
    int lo = t * CH;
    int hi = lo + CH; if (hi > n) hi = n;
    int s = 0;
    for (int i = lo; i < hi; ++i) s += deg[i];
    tsum[t] = s;
    __syncthreads();
    for (int d = 1; d < 1024; d <<= 1) {
        int v = (t >= d) ? tsum[t - d] : 0;
        __syncthreads();
        tsum[t] += v;
        __syncthreads();
    }
    int run = tsum[t] - s;  // exclusive prefix
    for (int i = lo; i < hi; ++i) { off[i] = run; run += deg[i]; }
    if (t == 1023) off[n] = tsum[1023];
}

__global__ __launch_bounds__(256) void fill_kernel(const int* __restrict__ ei,
                                                   const int* __restrict__ flag,
                                                   const int* __restrict__ off,
                                                   int* __restrict__ cursor,
                                                   int* __restrict__ srcs,
                                                   int* __restrict__ eidx, int E, int n) {
    int e = blockIdx.x * blockDim.x + threadIdx.x;
    if (e >= E) return;
    int is64 = *flag;
    int d = is64 ? ei[2 * ((size_t)E + e)] : ei[E + e];
    int s = is64 ? ei[2 * (size_t)e] : ei[e];
    if ((unsigned)d >= (unsigned)n || (unsigned)s >= (unsigned)n) return;
    int p = atomicAdd(&cursor[d], 1);
    int pos = off[d] + p;
    srcs[pos] = s;
    eidx[pos] = e;
}

// ---------------- W -> Wt bf16 transpose-convert: wt[l][n][k] = bf16(W[l][k][n]) ----

__global__ __launch_bounds__(256) void wt_kernel(const float* __restrict__ W1,
                                                 const float* __restrict__ W2,
                                                 unsigned short* __restrict__ wt) {
    int id = blockIdx.x * 256 + threadIdx.x;
    if (id >= 10 * 16384) return;
    int l = id >> 14;
    int rem = id & 16383;
    int nn = rem >> 7, kk = rem & 127;
    const float* base = (l < 5) ? (W1 + (size_t)l * 16384) : (W2 + (size_t)(l - 5) * 16384);
    wt[(size_t)l * 16384 + nn * 128 + kk] = f2bf(base[kk * 128 + nn]);
}

// ---------------- layer-0 aggregate (fp32 x/ea) fused with ea->bf16 CSR convert ----
// Frozen (r8/r9): at the measured 2.8 TB/s random-512B-row pattern ceiling.

__global__ __launch_bounds__(256) void agg_cvt_kernel(const float* __restrict__ x,
                                                      const float* __restrict__ ea,
                                                      const int* __restrict__ off,
                                                      const int* __restrict__ srcs,
                                                      const int* __restrict__ eidx,
                                                      uint32* __restrict__ eab,
                                                      uint32* __restrict__ out, int n) {
    int node = blockIdx.x * 4 + (threadIdx.x >> 6);
    if (node >= n) return;
    const int lane = threadIdx.x & 63;
    const int half = lane >> 5;
    const int q = lane & 31;
    f32x4 acc = {0.f, 0.f, 0.f, 0.f};
    int e = off[node];
    const int end = off[node + 1];
    while (e < end) {
        const int cnt = min(end - e, 64);
        const int sidx = (e + lane < end) ? srcs[e + lane] : 0;
        const int yidx = (e + lane < end) ? eidx[e + lane] : 0;
        int i = 0;
        for (; i + 4 <= cnt; i += 4) {
            const int iA = i + half, iB = i + 2 + half;
            const int sA = __shfl(sidx, iA), yA = __shfl(yidx, iA);
            const int sB = __shfl(sidx, iB), yB = __shfl(yidx, iB);
            f32x4 va = __builtin_nontemporal_load((const f32x4*)(ea + (size_t)yA * D + q * 4));
            f32x4 vb = __builtin_nontemporal_load((const f32x4*)(ea + (size_t)yB * D + q * 4));
            f32x4 ha = *(const f32x4*)(x + (size_t)sA * D + q * 4);
            f32x4 hb = *(const f32x4*)(x + (size_t)sB * D + q * 4);
#pragma unroll
            for (int k = 0; k < 4; ++k)
                acc[k] += fmaxf(ha[k] + va[k], 0.f) + fmaxf(hb[k] + vb[k], 0.f);
            u32x2 pa = {pack2(va[0], va[1]), pack2(va[2], va[3])};
            u32x2 pb = {pack2(vb[0], vb[1]), pack2(vb[2], vb[3])};
            *(u32x2*)(eab + (size_t)(e + iA) * 64 + q * 2) = pa;
            *(u32x2*)(eab + (size_t)(e + iB) * 64 + q * 2) = pb;
        }
        if (i + 2 <= cnt) {
            const int iA = i + half;
            const int sA = __shfl(sidx, iA), yA = __shfl(yidx, iA);
            f32x4 va = __builtin_nontemporal_load((const f32x4*)(ea + (size_t)yA * D + q * 4));
            f32x4 ha = *(const f32x4*)(x + (size_t)sA * D + q * 4);
#pragma unroll
            for (int k = 0; k < 4; ++k) acc[k] += fmaxf(ha[k] + va[k], 0.f);
            u32x2 pa = {pack2(va[0], va[1]), pack2(va[2], va[3])};
            *(u32x2*)(eab + (size_t)(e + iA) * 64 + q * 2) = pa;
            i += 2;
        }
        if (i < cnt) {  // exactly 1 left
            const int sA = __shfl(sidx, i), yA = __shfl(yidx, i);
            if (half == 0) {
                f32x4 va = __builtin_nontemporal_load((const f32x4*)(ea + (size_t)yA * D + q * 4));
                f32x4 ha = *(const f32x4*)(x + (size_t)sA * D + q * 4);
#pragma unroll
                for (int k = 0; k < 4; ++k) acc[k] += fmaxf(ha[k] + va[k], 0.f);
                u32x2 pa = {pack2(va[0], va[1]), pack2(va[2], va[3])};
                *(u32x2*)(eab + (size_t)(e + i) * 64 + q * 2) = pa;
            }
        }
        e += cnt;
    }
#pragma unroll
    for (int k = 0; k < 4; ++k) acc[k] += __shfl_xor(acc[k], 32);
    if (half == 0) {
        f32x4 xs = *(const f32x4*)(x + (size_t)node * D + q * 4);
        u32x2 o = {pack2(xs[0] + acc[0], xs[1] + acc[1]),
                   pack2(xs[2] + acc[2], xs[3] + acc[3])};
        *(u32x2*)(out + (size_t)node * 64 + q * 2) = o;
    }
}

// ---------------- aggregate (layers 1+): bf16 h/ea, index-preload + shfl (frozen) --

__global__ __launch_bounds__(256) void agg_kernel(const uint32* __restrict__ h,
                                                  const uint32* __restrict__ eab,
                                                  const int* __restrict__ off,
                                                  const int* __restrict__ srcs,
                                                  uint32* __restrict__ out, int n) {
    int node = blockIdx.x * 4 + (threadIdx.x >> 6);
    if (node >= n) return;
    const int lane = threadIdx.x & 63;
    const int g = lane >> 4;
    const int j = lane & 15;
    float acc[8] = {0.f, 0.f, 0.f, 0.f, 0.f, 0.f, 0.f, 0.f};
    int e = off[node];
    const int end = off[node + 1];
    while (e < end) {
        const int cnt = min(end - e, 64);
        const int sidx = (e + lane < end) ? srcs[e + lane] : 0;
        int i = 0;
        for (; i + 8 <= cnt; i += 8) {
            const int sA = __shfl(sidx, i + g);
            const int sB = __shfl(sidx, i + 4 + g);
            u32x4 a0 = *(const u32x4*)(eab + (size_t)(e + i + g) * 64 + j * 4);
            u32x4 a1 = *(const u32x4*)(eab + (size_t)(e + i + 4 + g) * 64 + j * 4);
            u32x4 h0 = *(const u32x4*)(h + (size_t)sA * 64 + j * 4);
            u32x4 h1 = *(const u32x4*)(h + (size_t)sB * 64 + j * 4);
#pragma unroll
            for (int k = 0; k < 4; ++k) {
                acc[2 * k]     += fmaxf(bflo(h0[k]) + bflo(a0[k]), 0.f)
                                + fmaxf(bflo(h1[k]) + bflo(a1[k]), 0.f);
                acc[2 * k + 1] += fmaxf(bfhi(h0[k]) + bfhi(a0[k]), 0.f)
                                + fmaxf(bfhi(h1[k]) + bfhi(a1[k]), 0.f);
            }
        }
        if (i + 4 <= cnt) {
            const int sA = __shfl(sidx, i + g);
            u32x4 a0 = *(const u32x4*)(eab + (size_t)(e + i + g) * 64 + j * 4);
            u32x4 h0 = *(const u32x4*)(h + (size_t)sA * 64 + j * 4);
#pragma unroll
            for (int k = 0; k < 4; ++k) {
                acc[2 * k]     += fmaxf(bflo(h0[k]) + bflo(a0[k]), 0.f);
                acc[2 * k + 1] += fmaxf(bfhi(h0[k]) + bfhi(a0[k]), 0.f);
            }
            i += 4;
        }
        const int rem = cnt - i;  // 0..3
        if (rem) {
            const int sA = __shfl(sidx, i + (g < rem ? g : 0));
            if (g < rem) {
                u32x4 a0 = *(const u32x4*)(eab + (size_t)(e + i + g) * 64 + j * 4);
                u32x4 h0 = *(const u32x4*)(h + (size_t)sA * 64 + j * 4);
#pragma unroll
                for (int k = 0; k < 4; ++k) {
                    acc[2 * k]     += fmaxf(bflo(h0[k]) + bflo(a0[k]), 0.f);
                    acc[2 * k + 1] += fmaxf(bfhi(h0[k]) + bfhi(a0[k]), 0.f);
                }
            }
        }
        e += cnt;
    }
#pragma unroll
    for (int k = 0; k < 8; ++k) {
        acc[k] += __shfl_xor(acc[k], 16);
        acc[k] += __shfl_xor(acc[k], 32);
    }
    if (g == 0) {
        u32x4 hn = *(const u32x4*)(h + (size_t)node * 64 + j * 4);
        u32x4 o;
#pragma unroll
        for (int k = 0; k < 4; ++k)
            o[k] = pack2(bflo(hn[k]) + acc[2 * k], bfhi(hn[k]) + acc[2 * k + 1]);
        *(u32x4*)(out + (size_t)node * 64 + j * 4) = o;
    }
}

// ---------------- FUSED MLP: gemm1 -> (grid barrier) BN -> gemm2, T in LDS ---------
// Persistent grid (<=512 blocks, co-resident: 256 thr, ~35KB LDS, launch_bounds(256,2)
// => 2 blocks/CU guaranteed). Phase 1: gemm1 per tile -> LDS (bf16, row stride 136 u16
// = 272B = 17*16B, 2-way bank aliasing = free), BN col stats in regs -> one device
// atomicAdd per block. Software grid barrier (threadfence + atomic arrive + acquire
// spin). Phase 2: BN scale/shift from colstats (agent-scope loads: plain loads could
// hit stale XCD-local L2), then gemm2 from LDS.
// mfma_f32_16x16x32_bf16: A row=l&15, k=8*(l>>4)+j; B col=l&15; D row=(l>>4)*4+r.

template <bool F32OUT>
__global__ __launch_bounds__(256, 2) void mlp_kernel(const uint4* __restrict__ A,
                                                     const uint4* __restrict__ Wt1,
                                                     const uint4* __restrict__ Wt2,
                                                     const float* __restrict__ b1,
                                                     const float* __restrict__ b2,
                                                     void* __restrict__ outp,
                                                     float* __restrict__ colstats,
                                                     const float* __restrict__ gamma,
                                                     const float* __restrict__ beta,
                                                     int* __restrict__ bar,
                                                     float inv_n, int n, int nTiles) {
    __shared__ __align__(16) unsigned short Tsm[2][64][136];
    __shared__ float red[256];
    const int t = threadIdx.x;
    const int wv = t >> 6, l = t & 63;
    const int lrow = l & 15, lk = l >> 4;

    red[t] = 0.f;
    __syncthreads();

    float sAcc[8] = {0, 0, 0, 0, 0, 0, 0, 0};
    float s2Acc[8] = {0, 0, 0, 0, 0, 0, 0, 0};

    // ---- phase 1: gemm1 (A global -> LDS tiles), stats in registers ----
#pragma unroll
    for (int slot = 0; slot < 2; ++slot) {
        const int tile = blockIdx.x + slot * gridDim.x;
        if (tile >= nTiles) break;
        const int r0 = tile * 64 + wv * 16;
        bf16x8 af[4];
        const int arow = r0 + lrow;
        const bool rowok = arow < n;
#pragma unroll
        for (int c = 0; c < 4; ++c) {
            union { uint4 u; bf16x8 v; } bu;
            bu.u = make_uint4(0u, 0u, 0u, 0u);
            if (rowok) bu.u = A[(size_t)arow * 16 + c * 4 + lk];
            af[c] = bu.v;
        }
#pragma unroll
        for (int n0 = 0; n0 < 8; ++n0) {
            const int wcol = n0 * 16 + lrow;
            f32x4 acc = {0.f, 0.f, 0.f, 0.f};
#pragma unroll
            for (int c = 0; c < 4; ++c) {
                union { uint4 u; bf16x8 v; } bu;
                bu.u = Wt1[wcol * 16 + c * 4 + lk];
                acc = __builtin_amdgcn_mfma_f32_16x16x32_bf16(af[c], bu.v, acc, 0, 0, 0);
            }
            const float bcol = b1[wcol];
#pragma unroll
            for (int r = 0; r < 4; ++r) {
                const int row = r0 + lk * 4 + r;
                const float v = acc[r] + bcol;
                if (row < n) {
                    Tsm[slot][wv * 16 + lk * 4 + r][wcol] = f2bf(v);
                    sAcc[n0] += v;
                    s2Acc[n0] += v * v;
                }
            }
        }
    }

    // ---- stats reduce: wave shfl -> LDS atomics -> one global atomic per col ----
#pragma unroll
    for (int n0 = 0; n0 < 8; ++n0) {
        const int wcol = n0 * 16 + lrow;
        float ls = sAcc[n0], ls2 = s2Acc[n0];
        ls  += __shfl_xor(ls, 16);  ls  += __shfl_xor(ls, 32);
        ls2 += __shfl_xor(ls2, 16); ls2 += __shfl_xor(ls2, 32);
        if (lk == 0) {
            atomicAdd(&red[wcol], ls);
            atomicAdd(&red[D + wcol], ls2);
        }
    }
    __syncthreads();
    if (t < 128) {
        atomicAdd(&colstats[t], red[t]);
        atomicAdd(&colstats[D + t], red[D + t]);
    }

    // ---- software grid barrier ----
    __threadfence();   // every thread: order its colstats atomics before arrive
    __syncthreads();
    if (t == 0) {
        atomicAdd(bar, 1);
        while (__hip_atomic_load(bar, __ATOMIC_ACQUIRE, __HIP_MEMORY_SCOPE_AGENT) <
               (int)gridDim.x) {}
    }
    __syncthreads();

    // ---- BN scale/shift from complete colstats (agent-scope loads) ----
    if (t < 128) {
        float cs  = __hip_atomic_load(&colstats[t], __ATOMIC_RELAXED,
                                      __HIP_MEMORY_SCOPE_AGENT);
        float cs2 = __hip_atomic_load(&colstats[128 + t], __ATOMIC_RELAXED,
                                      __HIP_MEMORY_SCOPE_AGENT);
        float mu = cs * inv_n;
        float var = cs2 * inv_n - mu * mu;
        float inv = rsqrtf(var + BN_EPS);
        float sc = gamma[t] * inv;
        red[t] = sc;
        red[128 + t] = beta[t] - mu * sc;
    }
    __syncthreads();

    // ---- phase 2: gemm2 from LDS tiles ----
    float* outF = (float*)outp;
    unsigned short* outB = (unsigned short*)outp;
#pragma unroll
    for (int slot = 0; slot < 2; ++slot) {
        const int tile = blockIdx.x + slot * gridDim.x;
        if (tile >= nTiles) break;
        const int r0 = tile * 64 + wv * 16;
        bf16x8 af[4];
#pragma unroll
        for (int c = 0; c < 4; ++c) {
            union { uint4 u; bf16x8 v; uint32 w[4]; } bu;
            bu.u = *(const uint4*)&Tsm[slot][wv * 16 + lrow][(c * 4 + lk) * 8];
            const int kb = c * 32 + lk * 8;
            float xv[8];
#pragma unroll
            for (int i = 0; i < 4; ++i) {
                xv[2 * i]     = bflo(bu.w[i]);
                xv[2 * i + 1] = bfhi(bu.w[i]);
            }
#pragma unroll
            for (int j = 0; j < 8; ++j)
                xv[j] = fmaxf(fmaf(red[kb + j], xv[j], red[128 + kb + j]), 0.f);
#pragma unroll
            for (int i = 0; i < 4; ++i)
                bu.w[i] = pack2(xv[2 * i], xv[2 * i + 1]);
            af[c] = bu.v;
        }
#pragma unroll
        for (int n0 = 0; n0 < 8; ++n0) {
            const int wcol = n0 * 16 + lrow;
            f32x4 acc = {0.f, 0.f, 0.f, 0.f};
#pragma unroll
            for (int c = 0; c < 4; ++c) {
                union { uint4 u; bf16x8 v; } bu;
                bu.u = Wt2[wcol * 16 + c * 4 + lk];
                acc = __builtin_amdgcn_mfma_f32_16x16x32_bf16(af[c], bu.v, acc, 0, 0, 0);
            }
            const float bcol = b2[wcol];
#pragma unroll
            for (int r = 0; r < 4; ++r) {
                const int row = r0 + lk * 4 + r;
                const float v = acc[r] + bcol;
                if (row < n) {
                    if (F32OUT) outF[(size_t)row * D + wcol] = v;
                    else        outB[(size_t)row * D + wcol] = f2bf(v);
                }
            }
        }
    }
}

// ---------------- launch ----------------

extern "C" void kernel_launch(void* const* d_in, const int* in_sizes, int n_in,
                              void* d_out, int out_size, void* d_ws, size_t ws_size,
                              hipStream_t stream) {
    const float* x      = (const float*)d_in[0];
    const int*   ei     = (const int*)d_in[1];
    const float* ea     = (const float*)d_in[2];
    const float* W1     = (const float*)d_in[3];
    const float* b1     = (const float*)d_in[4];
    const float* gamma  = (const float*)d_in[5];
    const float* beta   = (const float*)d_in[6];
    const float* W2     = (const float*)d_in[7];
    const float* b2     = (const float*)d_in[8];
    const int N = in_sizes[0] / D;
    const int E = in_sizes[1] / 2;

    char* w = (char*)d_ws;
    auto alloc = [&](size_t bytes) {
        char* p = w;
        w += (bytes + 255) & ~(size_t)255;
        return p;
    };
    int*    off      = (int*)alloc((size_t)(N + 1) * sizeof(int));
    // single zeroed region: deg[N] | cursor[N] | colstats[5*256] | barrier[8]
    int*    zbase    = (int*)alloc(((size_t)2 * N + 5 * 256 + 8) * sizeof(int));
    int*    deg      = zbase;
    int*    cursor   = zbase + N;
    float*  colstats = (float*)(zbase + 2 * N);
    int*    bar      = zbase + 2 * N + 5 * 256;
    int*    flag     = (int*)alloc(256);
    unsigned short* wt = (unsigned short*)alloc(10 * 16384 * sizeof(unsigned short));
    int*    srcs     = (int*)alloc((size_t)E * sizeof(int));
    int*    eidx     = (int*)alloc((size_t)E * sizeof(int));
    uint32* eab      = (uint32*)alloc((size_t)E * 64 * sizeof(uint32));
    uint32* G        = (uint32*)alloc((size_t)N * 64 * sizeof(uint32));  // agg out (bf16)
    uint32* H        = (uint32*)alloc((size_t)N * 64 * sizeof(uint32));  // mlp out (bf16)

    wt_kernel<<<(10 * 16384 + 255) / 256, 256, 0, stream>>>(W1, W2, wt);
    detect_kernel<<<1, 64, 0, stream>>>(ei, flag);
    hipMemsetAsync(zbase, 0, ((size_t)2 * N + 5 * 256 + 8) * sizeof(int), stream);
    hist_kernel<<<(E + 255) / 256, 256, 0, stream>>>(ei, flag, deg, E, N);
    scan_kernel<<<1, 1024, 0, stream>>>(deg, off, N);
    fill_kernel<<<(E + 255) / 256, 256, 0, stream>>>(ei, flag, off, cursor, srcs, eidx, E, N);

    const int nTiles    = (N + 63) / 64;
    const int gemmGrid  = nTiles < 512 ? nTiles : 512;  // persistent, co-resident
    const int aggBlocks = (N + 3) / 4;
    const float inv_n = 1.0f / (float)N;

    const uint32* hin = nullptr;
    for (int l = 0; l < LAYERS; ++l) {
        float* cst = colstats + l * 256;
        const uint4* wt1 = (const uint4*)(wt + (size_t)l * 16384);
        const uint4* wt2 = (const uint4*)(wt + (size_t)(5 + l) * 16384);
        if (l == 0)
            agg_cvt_kernel<<<aggBlocks, 256, 0, stream>>>(x, ea, off, srcs, eidx, eab, G, N);
        else
            agg_kernel<<<aggBlocks, 256, 0, stream>>>(hin, eab, off, srcs, G, N);
        if (l < LAYERS - 1)
            mlp_kernel<false><<<gemmGrid, 256, 0, stream>>>(
                (const uint4*)G, wt1, wt2, b1 + l * D, b2 + l * D, H, cst,
                gamma + l * D, beta + l * D, bar + l, inv_n, N, nTiles);
        else
            mlp_kernel<true><<<gemmGrid, 256, 0, stream>>>(
                (const uint4*)G, wt1, wt2, b1 + l * D, b2 + l * D, d_out, cst,
                gamma + l * D, beta + l * D, bar + l, inv_n, N, nTiles);
        hin = H;
    }
}

// Round 12
// 681.128 us; speedup vs baseline: 1.3587x; 1.3587x over previous
//
#include <hip/hip_runtime.h>
#include <hip/hip_bf16.h>
#include <stdint.h>

#define D 128
#define LAYERS 5
#define BN_EPS 1e-5f

typedef unsigned int uint32;
typedef __bf16 bf16x8 __attribute__((ext_vector_type(8)));
typedef float f32x4 __attribute__((ext_vector_type(4)));
typedef float f32x2 __attribute__((ext_vector_type(2)));
typedef uint32 u32x2 __attribute__((ext_vector_type(2)));
typedef uint32 u32x4 __attribute__((ext_vector_type(4)));

// fp32 -> bf16 bits, round-to-nearest-even
__device__ inline unsigned short f2bf(float f) {
    uint32 u = __float_as_uint(f);
    return (unsigned short)((u + 0x7fffu + ((u >> 16) & 1u)) >> 16);
}
__device__ inline float bflo(uint32 p) { return __uint_as_float(p << 16); }
__device__ inline float bfhi(uint32 p) { return __uint_as_float(p & 0xffff0000u); }
__device__ inline uint32 pack2(float a, float b) {
    return (uint32)f2bf(a) | ((uint32)f2bf(b) << 16);
}

// ---------------- edge_index layout detection ----------------

__global__ void detect_kernel(const int* __restrict__ ei, int* __restrict__ flag) {
    if (threadIdx.x == 0 && blockIdx.x == 0) {
        int allz = 1;
#pragma unroll
        for (int i = 0; i < 16; ++i) allz &= (ei[2 * i + 1] == 0);
        *flag = allz;  // 1 => int64 layout, 0 => int32 layout
    }
}

// ---------------- CSR build (dst -> incoming edges) ----------------

__global__ __launch_bounds__(256) void hist_kernel(const int* __restrict__ ei,
                                                   const int* __restrict__ flag,
                                                   int* __restrict__ deg, int E, int n) {
    int e = blockIdx.x * blockDim.x + threadIdx.x;
    if (e >= E) return;
    int is64 = *flag;
    int d = is64 ? ei[2 * ((size_t)E + e)] : ei[E + e];
    if ((unsigned)d < (unsigned)n) atomicAdd(&deg[d], 1);
}

__global__ __launch_bounds__(1024) void scan_kernel(const int* __restrict__ deg,
                                                    int* __restrict__ off, int n) {
    __shared__ int tsum[1024];
    int t = threadIdx.x;
    int CH = (n + 1023) >> 10;
    int lo = t * CH;
    int hi = lo + CH; if (hi > n) hi = n;
    int s = 0;
    for (int i = lo; i < hi; ++i) s += deg[i];
    tsum[t] = s;
    __syncthreads();
    for (int d = 1; d < 1024; d <<= 1) {
        int v = (t >= d) ? tsum[t - d] : 0;
        __syncthreads();
        tsum[t] += v;
        __syncthreads();
    }
    int run = tsum[t] - s;  // exclusive prefix
    for (int i = lo; i < hi; ++i) { off[i] = run; run += deg[i]; }
    if (t == 1023) off[n] = tsum[1023];
}

__global__ __launch_bounds__(256) void fill_kernel(const int* __restrict__ ei,
                                                   const int* __restrict__ flag,
                                                   const int* __restrict__ off,
                                                   int* __restrict__ cursor,
                                                   int* __restrict__ srcs,
                                                   int* __restrict__ eidx, int E, int n) {
    int e = blockIdx.x * blockDim.x + threadIdx.x;
    if (e >= E) return;
    int is64 = *flag;
    int d = is64 ? ei[2 * ((size_t)E + e)] : ei[E + e];
    int s = is64 ? ei[2 * (size_t)e] : ei[e];
    if ((unsigned)d >= (unsigned)n || (unsigned)s >= (unsigned)n) return;
    int p = atomicAdd(&cursor[d], 1);
    int pos = off[d] + p;
    srcs[pos] = s;
    eidx[pos] = e;
}

// ---------------- W -> Wt bf16 transpose-convert: wt[l][n][k] = bf16(W[l][k][n]) ----

__global__ __launch_bounds__(256) void wt_kernel(const float* __restrict__ W1,
                                                 const float* __restrict__ W2,
                                                 unsigned short* __restrict__ wt) {
    int id = blockIdx.x * 256 + threadIdx.x;
    if (id >= 10 * 16384) return;
    int l = id >> 14;
    int rem = id & 16383;
    int nn = rem >> 7, kk = rem & 127;
    const float* base = (l < 5) ? (W1 + (size_t)l * 16384) : (W2 + (size_t)(l - 5) * 16384);
    wt[(size_t)l * 16384 + nn * 128 + kk] = f2bf(base[kk * 128 + nn]);
}

// ---------------- layer-0 aggregate (fp32 x/ea) fused with ea->bf16 CSR convert ----
// Frozen (r8/r9): at the measured 2.8 TB/s random-512B-row pattern ceiling.

__global__ __launch_bounds__(256) void agg_cvt_kernel(const float* __restrict__ x,
                                                      const float* __restrict__ ea,
                                                      const int* __restrict__ off,
                                                      const int* __restrict__ srcs,
                                                      const int* __restrict__ eidx,
                                                      uint32* __restrict__ eab,
                                                      uint32* __restrict__ out, int n) {
    int node = blockIdx.x * 4 + (threadIdx.x >> 6);
    if (node >= n) return;
    const int lane = threadIdx.x & 63;
    const int half = lane >> 5;
    const int q = lane & 31;
    f32x4 acc = {0.f, 0.f, 0.f, 0.f};
    int e = off[node];
    const int end = off[node + 1];
    while (e < end) {
        const int cnt = min(end - e, 64);
        const int sidx = (e + lane < end) ? srcs[e + lane] : 0;
        const int yidx = (e + lane < end) ? eidx[e + lane] : 0;
        int i = 0;
        for (; i + 4 <= cnt; i += 4) {
            const int iA = i + half, iB = i + 2 + half;
            const int sA = __shfl(sidx, iA), yA = __shfl(yidx, iA);
            const int sB = __shfl(sidx, iB), yB = __shfl(yidx, iB);
            f32x4 va = __builtin_nontemporal_load((const f32x4*)(ea + (size_t)yA * D + q * 4));
            f32x4 vb = __builtin_nontemporal_load((const f32x4*)(ea + (size_t)yB * D + q * 4));
            f32x4 ha = *(const f32x4*)(x + (size_t)sA * D + q * 4);
            f32x4 hb = *(const f32x4*)(x + (size_t)sB * D + q * 4);
#pragma unroll
            for (int k = 0; k < 4; ++k)
                acc[k] += fmaxf(ha[k] + va[k], 0.f) + fmaxf(hb[k] + vb[k], 0.f);
            u32x2 pa = {pack2(va[0], va[1]), pack2(va[2], va[3])};
            u32x2 pb = {pack2(vb[0], vb[1]), pack2(vb[2], vb[3])};
            *(u32x2*)(eab + (size_t)(e + iA) * 64 + q * 2) = pa;
            *(u32x2*)(eab + (size_t)(e + iB) * 64 + q * 2) = pb;
        }
        if (i + 2 <= cnt) {
            const int iA = i + half;
            const int sA = __shfl(sidx, iA), yA = __shfl(yidx, iA);
            f32x4 va = __builtin_nontemporal_load((const f32x4*)(ea + (size_t)yA * D + q * 4));
            f32x4 ha = *(const f32x4*)(x + (size_t)sA * D + q * 4);
#pragma unroll
            for (int k = 0; k < 4; ++k) acc[k] += fmaxf(ha[k] + va[k], 0.f);
            u32x2 pa = {pack2(va[0], va[1]), pack2(va[2], va[3])};
            *(u32x2*)(eab + (size_t)(e + iA) * 64 + q * 2) = pa;
            i += 2;
        }
        if (i < cnt) {  // exactly 1 left
            const int sA = __shfl(sidx, i), yA = __shfl(yidx, i);
            if (half == 0) {
                f32x4 va = __builtin_nontemporal_load((const f32x4*)(ea + (size_t)yA * D + q * 4));
                f32x4 ha = *(const f32x4*)(x + (size_t)sA * D + q * 4);
#pragma unroll
                for (int k = 0; k < 4; ++k) acc[k] += fmaxf(ha[k] + va[k], 0.f);
                u32x2 pa = {pack2(va[0], va[1]), pack2(va[2], va[3])};
                *(u32x2*)(eab + (size_t)(e + i) * 64 + q * 2) = pa;
            }
        }
        e += cnt;
    }
#pragma unroll
    for (int k = 0; k < 4; ++k) acc[k] += __shfl_xor(acc[k], 32);
    if (half == 0) {
        f32x4 xs = *(const f32x4*)(x + (size_t)node * D + q * 4);
        u32x2 o = {pack2(xs[0] + acc[0], xs[1] + acc[1]),
                   pack2(xs[2] + acc[2], xs[3] + acc[3])};
        *(u32x2*)(out + (size_t)node * 64 + q * 2) = o;
    }
}

// ---------------- aggregate (layers 1+): bf16 h/ea, index-preload + shfl (frozen) --

__global__ __launch_bounds__(256) void agg_kernel(const uint32* __restrict__ h,
                                                  const uint32* __restrict__ eab,
                                                  const int* __restrict__ off,
                                                  const int* __restrict__ srcs,
                                                  uint32* __restrict__ out, int n) {
    int node = blockIdx.x * 4 + (threadIdx.x >> 6);
    if (node >= n) return;
    const int lane = threadIdx.x & 63;
    const int g = lane >> 4;
    const int j = lane & 15;
    float acc[8] = {0.f, 0.f, 0.f, 0.f, 0.f, 0.f, 0.f, 0.f};
    int e = off[node];
    const int end = off[node + 1];
    while (e < end) {
        const int cnt = min(end - e, 64);
        const int sidx = (e + lane < end) ? srcs[e + lane] : 0;
        int i = 0;
        for (; i + 8 <= cnt; i += 8) {
            const int sA = __shfl(sidx, i + g);
            const int sB = __shfl(sidx, i + 4 + g);
            u32x4 a0 = *(const u32x4*)(eab + (size_t)(e + i + g) * 64 + j * 4);
            u32x4 a1 = *(const u32x4*)(eab + (size_t)(e + i + 4 + g) * 64 + j * 4);
            u32x4 h0 = *(const u32x4*)(h + (size_t)sA * 64 + j * 4);
            u32x4 h1 = *(const u32x4*)(h + (size_t)sB * 64 + j * 4);
#pragma unroll
            for (int k = 0; k < 4; ++k) {
                acc[2 * k]     += fmaxf(bflo(h0[k]) + bflo(a0[k]), 0.f)
                                + fmaxf(bflo(h1[k]) + bflo(a1[k]), 0.f);
                acc[2 * k + 1] += fmaxf(bfhi(h0[k]) + bfhi(a0[k]), 0.f)
                                + fmaxf(bfhi(h1[k]) + bfhi(a1[k]), 0.f);
            }
        }
        if (i + 4 <= cnt) {
            const int sA = __shfl(sidx, i + g);
            u32x4 a0 = *(const u32x4*)(eab + (size_t)(e + i + g) * 64 + j * 4);
            u32x4 h0 = *(const u32x4*)(h + (size_t)sA * 64 + j * 4);
#pragma unroll
            for (int k = 0; k < 4; ++k) {
                acc[2 * k]     += fmaxf(bflo(h0[k]) + bflo(a0[k]), 0.f);
                acc[2 * k + 1] += fmaxf(bfhi(h0[k]) + bfhi(a0[k]), 0.f);
            }
            i += 4;
        }
        const int rem = cnt - i;  // 0..3
        if (rem) {
            const int sA = __shfl(sidx, i + (g < rem ? g : 0));
            if (g < rem) {
                u32x4 a0 = *(const u32x4*)(eab + (size_t)(e + i + g) * 64 + j * 4);
                u32x4 h0 = *(const u32x4*)(h + (size_t)sA * 64 + j * 4);
#pragma unroll
                for (int k = 0; k < 4; ++k) {
                    acc[2 * k]     += fmaxf(bflo(h0[k]) + bflo(a0[k]), 0.f);
                    acc[2 * k + 1] += fmaxf(bfhi(h0[k]) + bfhi(a0[k]), 0.f);
                }
            }
        }
        e += cnt;
    }
#pragma unroll
    for (int k = 0; k < 8; ++k) {
        acc[k] += __shfl_xor(acc[k], 16);
        acc[k] += __shfl_xor(acc[k], 32);
    }
    if (g == 0) {
        u32x4 hn = *(const u32x4*)(h + (size_t)node * 64 + j * 4);
        u32x4 o;
#pragma unroll
        for (int k = 0; k < 4; ++k)
            o[k] = pack2(bflo(hn[k]) + acc[2 * k], bfhi(hn[k]) + acc[2 * k + 1]);
        *(u32x4*)(out + (size_t)node * 64 + j * 4) = o;
    }
}

// ---------------- MFMA GEMM (PERSISTENT): out = f(A) @ W + bias --------------------
// Grid-stride over 64-row tiles. MODE 1: f=id, BN col stats accumulated in REGISTERS
// across the block's tiles, reduced + atomically added to colstats ONCE per block.
// MODE 2: f(x)=relu(sc*x+sh), sc/sh from colstats (BN folded). F32OUT: final layer.
// mfma_f32_16x16x32_bf16: A row=l&15, k=8*(l>>4)+j; B col=l&15; D row=(l>>4)*4+r.

template <int MODE, bool F32OUT>
__global__ __launch_bounds__(256) void gemm_kernel(const uint4* __restrict__ A,
                                                   const uint4* __restrict__ Wt4,
                                                   const float* __restrict__ bias,
                                                   void* __restrict__ outp,
                                                   float* __restrict__ colstats,
                                                   const float* __restrict__ gamma,
                                                   const float* __restrict__ beta,
                                                   float inv_n, int n, int nTiles) {
    __shared__ float red[256];
    const int t = threadIdx.x;
    const int wv = t >> 6, l = t & 63;
    const int lrow = l & 15, lk = l >> 4;

    if (MODE == 1) {
        red[t] = 0.f;
    } else {
        if (t < 128) {
            float mu = colstats[t] * inv_n;
            float var = colstats[128 + t] * inv_n - mu * mu;
            float inv = rsqrtf(var + BN_EPS);
            float sc = gamma[t] * inv;
            red[t] = sc;
            red[128 + t] = beta[t] - mu * sc;
        }
    }
    __syncthreads();

    float* outF = (float*)outp;
    unsigned short* outB = (unsigned short*)outp;
    float sAcc[8] = {0, 0, 0, 0, 0, 0, 0, 0};
    float s2Acc[8] = {0, 0, 0, 0, 0, 0, 0, 0};

    for (int tile = blockIdx.x; tile < nTiles; tile += gridDim.x) {
        const int r0 = tile * 64 + wv * 16;

        // A fragments for the wave's 16 rows, all K=128 (4 chunks of 32)
        bf16x8 af[4];
        const int arow = r0 + lrow;
        const bool rowok = arow < n;
#pragma unroll
        for (int c = 0; c < 4; ++c) {
            union { uint4 u; bf16x8 v; uint32 w[4]; } bu;
            bu.u = make_uint4(0u, 0u, 0u, 0u);
            if (rowok) bu.u = A[(size_t)arow * 16 + c * 4 + lk];
            if (MODE == 2) {
                const int kb = c * 32 + lk * 8;
                float xv[8];
#pragma unroll
                for (int i = 0; i < 4; ++i) {
                    xv[2 * i]     = bflo(bu.w[i]);
                    xv[2 * i + 1] = bfhi(bu.w[i]);
                }
#pragma unroll
                for (int j = 0; j < 8; ++j)
                    xv[j] = fmaxf(fmaf(red[kb + j], xv[j], red[128 + kb + j]), 0.f);
#pragma unroll
                for (int i = 0; i < 4; ++i)
                    bu.w[i] = pack2(xv[2 * i], xv[2 * i + 1]);
            }
            af[c] = bu.v;
        }

#pragma unroll
        for (int n0 = 0; n0 < 8; ++n0) {
            const int wcol = n0 * 16 + lrow;
            f32x4 acc = {0.f, 0.f, 0.f, 0.f};
#pragma unroll
            for (int c = 0; c < 4; ++c) {
                union { uint4 u; bf16x8 v; } bu;
                bu.u = Wt4[wcol * 16 + c * 4 + lk];
                acc = __builtin_amdgcn_mfma_f32_16x16x32_bf16(af[c], bu.v, acc, 0, 0, 0);
            }
            const float bcol = bias[wcol];
#pragma unroll
            for (int r = 0; r < 4; ++r) {
                int row = r0 + lk * 4 + r;
                float v = acc[r] + bcol;
                if (row < n) {
                    if (F32OUT) outF[(size_t)row * D + wcol] = v;
                    else        outB[(size_t)row * D + wcol] = f2bf(v);
                    if (MODE == 1) { sAcc[n0] += v; s2Acc[n0] += v * v; }
                }
            }
        }
    }

    if (MODE == 1) {
#pragma unroll
        for (int n0 = 0; n0 < 8; ++n0) {
            const int wcol = n0 * 16 + lrow;
            float ls = sAcc[n0], ls2 = s2Acc[n0];
            ls  += __shfl_xor(ls, 16);  ls  += __shfl_xor(ls, 32);
            ls2 += __shfl_xor(ls2, 16); ls2 += __shfl_xor(ls2, 32);
            if (lk == 0) {
                atomicAdd(&red[wcol], ls);
                atomicAdd(&red[D + wcol], ls2);
            }
        }
        __syncthreads();
        if (t < 128) {
            atomicAdd(&colstats[t], red[t]);
            atomicAdd(&colstats[D + t], red[D + t]);
        }
    }
}

// ---------------- launch ----------------

extern "C" void kernel_launch(void* const* d_in, const int* in_sizes, int n_in,
                              void* d_out, int out_size, void* d_ws, size_t ws_size,
                              hipStream_t stream) {
    const float* x      = (const float*)d_in[0];
    const int*   ei     = (const int*)d_in[1];
    const float* ea     = (const float*)d_in[2];
    const float* W1     = (const float*)d_in[3];
    const float* b1     = (const float*)d_in[4];
    const float* gamma  = (const float*)d_in[5];
    const float* beta   = (const float*)d_in[6];
    const float* W2     = (const float*)d_in[7];
    const float* b2     = (const float*)d_in[8];
    const int N = in_sizes[0] / D;
    const int E = in_sizes[1] / 2;

    char* w = (char*)d_ws;
    auto alloc = [&](size_t bytes) {
        char* p = w;
        w += (bytes + 255) & ~(size_t)255;
        return p;
    };
    int*    off      = (int*)alloc((size_t)(N + 1) * sizeof(int));
    // single zeroed region: deg[N] | cursor[N] | colstats[5*256]
    int*    zbase    = (int*)alloc(((size_t)2 * N + 5 * 256) * sizeof(int));
    int*    deg      = zbase;
    int*    cursor   = zbase + N;
    float*  colstats = (float*)(zbase + 2 * N);
    int*    flag     = (int*)alloc(256);
    unsigned short* wt = (unsigned short*)alloc(10 * 16384 * sizeof(unsigned short));
    int*    srcs     = (int*)alloc((size_t)E * sizeof(int));
    int*    eidx     = (int*)alloc((size_t)E * sizeof(int));
    uint32* eab      = (uint32*)alloc((size_t)E * 64 * sizeof(uint32));
    uint32* G        = (uint32*)alloc((size_t)N * 64 * sizeof(uint32));  // agg out (bf16)
    uint32* T        = (uint32*)alloc((size_t)N * 64 * sizeof(uint32));  // gemm1 out (bf16)
    uint32* H        = (uint32*)alloc((size_t)N * 64 * sizeof(uint32));  // gemm2 out (bf16)

    wt_kernel<<<(10 * 16384 + 255) / 256, 256, 0, stream>>>(W1, W2, wt);
    detect_kernel<<<1, 64, 0, stream>>>(ei, flag);
    hipMemsetAsync(zbase, 0, ((size_t)2 * N + 5 * 256) * sizeof(int), stream);
    hist_kernel<<<(E + 255) / 256, 256, 0, stream>>>(ei, flag, deg, E, N);
    scan_kernel<<<1, 1024, 0, stream>>>(deg, off, N);
    fill_kernel<<<(E + 255) / 256, 256, 0, stream>>>(ei, flag, off, cursor, srcs, eidx, E, N);

    const int nTiles    = (N + 63) / 64;
    const int gemmGrid  = nTiles < 512 ? nTiles : 512;  // persistent grid
    const int aggBlocks = (N + 3) / 4;
    const float inv_n = 1.0f / (float)N;

    const uint32* hin = nullptr;
    for (int l = 0; l < LAYERS; ++l) {
        float* cst = colstats + l * 256;
        const uint4* wt1 = (const uint4*)(wt + (size_t)l * 16384);
        const uint4* wt2 = (const uint4*)(wt + (size_t)(5 + l) * 16384);
        if (l == 0)
            agg_cvt_kernel<<<aggBlocks, 256, 0, stream>>>(x, ea, off, srcs, eidx, eab, G, N);
        else
            agg_kernel<<<aggBlocks, 256, 0, stream>>>(hin, eab, off, srcs, G, N);
        gemm_kernel<1, false><<<gemmGrid, 256, 0, stream>>>(
            (const uint4*)G, wt1, b1 + l * D, T, cst, nullptr, nullptr, inv_n, N, nTiles);
        if (l < LAYERS - 1)
            gemm_kernel<2, false><<<gemmGrid, 256, 0, stream>>>(
                (const uint4*)T, wt2, b2 + l * D, H, cst,
                gamma + l * D, beta + l * D, inv_n, N, nTiles);
        else
            gemm_kernel<2, true><<<gemmGrid, 256, 0, stream>>>(
                (const uint4*)T, wt2, b2 + l * D, d_out, cst,
                gamma + l * D, beta + l * D, inv_n, N, nTiles);
        hin = H;
    }
}